// Round 2
// baseline (3929.330 us; speedup 1.0000x reference)
//
#include <hip/hip_runtime.h>

#define NB 128
#define NS 256
#define NI 64
#define NH 128
#define NL 64
#define NG 384  // 3*NH

__device__ __forceinline__ float fast_tanh(float x) {
    float e = __expf(2.0f * x);
    return 1.0f - 2.0f / (e + 1.0f);
}
__device__ __forceinline__ float fast_sig(float x) {
    return 1.0f / (1.0f + __expf(-x));
}
__device__ __forceinline__ float quad_red(float a) {
    a += __shfl_xor(a, 1);
    a += __shfl_xor(a, 2);
    return a;
}

// ---------------------------------------------------------------------------
// GX precompute: gx[s][b][j] = b_ih[j] + sum_c x[b][s][c] * W_ih[j][c]
// One block per s; W_ih rows cached in registers; x staged in LDS.
// ---------------------------------------------------------------------------
__global__ __launch_bounds__(384)
void gx_kernel(const float* __restrict__ x, const float* __restrict__ W_ih,
               const float* __restrict__ b_ih, float* __restrict__ gx)
{
    const int s = blockIdx.x;           // 0..255
    const int j = threadIdx.x;          // 0..383
    __shared__ __align__(16) float xs[NB * NI];  // 32 KB
    for (int idx = j; idx < NB * NI; idx += 384) {
        int bb = idx >> 6, cc = idx & 63;
        xs[idx] = x[(bb * NS + s) * NI + cc];
    }
    float w[64];
#pragma unroll
    for (int c = 0; c < 64; c += 4)
        *(float4*)&w[c] = *(const float4*)&W_ih[j * NI + c];
    const float bj = b_ih[j];
    __syncthreads();
    for (int bb = 0; bb < NB; bb++) {
        const float* xr = xs + bb * NI;
        float a0 = 0.f, a1 = 0.f, a2 = 0.f, a3 = 0.f;
#pragma unroll
        for (int c = 0; c < 64; c += 4) {
            a0 = fmaf(w[c + 0], xr[c + 0], a0);
            a1 = fmaf(w[c + 1], xr[c + 1], a1);
            a2 = fmaf(w[c + 2], xr[c + 2], a2);
            a3 = fmaf(w[c + 3], xr[c + 3], a3);
        }
        gx[((size_t)s * NB + bb) * NG + j] = ((a0 + a1) + (a2 + a3)) + bj;
    }
}

// ---------------------------------------------------------------------------
// Setup: W12 = W1@W2 [128x128], Whh2 = Whh@W2 [384x128],
//        w1b2 = W1@b2 [128],   whhb2 = Whh@b2 [384]
// grid 512 blocks x 128 threads; block i<128 -> W1 row i, else Whh row i-128.
// ---------------------------------------------------------------------------
__global__ __launch_bounds__(128)
void prep_kernel(const float* __restrict__ W1, const float* __restrict__ Whh,
                 const float* __restrict__ W2, const float* __restrict__ b2,
                 float* __restrict__ W12, float* __restrict__ Whh2,
                 float* __restrict__ w1b2, float* __restrict__ whhb2)
{
    const int i = blockIdx.x;   // 0..511
    const int j = threadIdx.x;  // 0..127
    __shared__ float rowA[NH];
    __shared__ float red[NH];
    const float* src = (i < NH) ? (W1 + i * NH) : (Whh + (size_t)(i - NH) * NH);
    rowA[j] = src[j];
    __syncthreads();
    float acc = 0.f;
    for (int k = 0; k < NH; k++) acc = fmaf(rowA[k], W2[k * NH + j], acc);
    if (i < NH) W12[i * NH + j] = acc;
    else        Whh2[(size_t)(i - NH) * NH + j] = acc;
    red[j] = rowA[j] * b2[j];
    __syncthreads();
    for (int off = 64; off > 0; off >>= 1) {
        if (j < off) red[j] += red[j + off];
        __syncthreads();
    }
    if (j == 0) {
        if (i < NH) w1b2[i] = red[0];
        else        whhb2[i - NH] = red[0];
    }
}

// ---------------------------------------------------------------------------
// Matvec helpers. co[8] = per-lane rotated float offsets (conflict-free).
// All weight arrays are pre-rotated identically at load time.
// ---------------------------------------------------------------------------
__device__ __forceinline__ float mv32(const float* __restrict__ W,
                                      const float* __restrict__ src,
                                      const int co[8])
{
    float a0 = 0.f, a1 = 0.f, a2 = 0.f, a3 = 0.f;
#pragma unroll
    for (int jj = 0; jj < 8; jj++) {
        float4 v = *(const float4*)(src + co[jj]);
        a0 = fmaf(W[4 * jj + 0], v.x, a0);
        a1 = fmaf(W[4 * jj + 1], v.y, a1);
        a2 = fmaf(W[4 * jj + 2], v.z, a2);
        a3 = fmaf(W[4 * jj + 3], v.w, a3);
    }
    return quad_red((a0 + a1) + (a2 + a3));
}

// two weights, one shared source
__device__ __forceinline__ void mv32_pair1(const float* __restrict__ Wa,
                                           const float* __restrict__ Wb,
                                           const float* __restrict__ src,
                                           const int co[8], float& oa, float& ob)
{
    float a0 = 0.f, a1 = 0.f, b0 = 0.f, b1 = 0.f;
#pragma unroll
    for (int jj = 0; jj < 8; jj++) {
        float4 v = *(const float4*)(src + co[jj]);
        a0 = fmaf(Wa[4 * jj + 0], v.x, a0);
        a1 = fmaf(Wa[4 * jj + 1], v.y, a1);
        a0 = fmaf(Wa[4 * jj + 2], v.z, a0);
        a1 = fmaf(Wa[4 * jj + 3], v.w, a1);
        b0 = fmaf(Wb[4 * jj + 0], v.x, b0);
        b1 = fmaf(Wb[4 * jj + 1], v.y, b1);
        b0 = fmaf(Wb[4 * jj + 2], v.z, b0);
        b1 = fmaf(Wb[4 * jj + 3], v.w, b1);
    }
    oa = quad_red(a0 + a1);
    ob = quad_red(b0 + b1);
}

// two weights, two sources
__device__ __forceinline__ void mv32_pair2(const float* __restrict__ Wa,
                                           const float* __restrict__ srcA,
                                           const float* __restrict__ Wb,
                                           const float* __restrict__ srcB,
                                           const int co[8], float& oa, float& ob)
{
    float a0 = 0.f, a1 = 0.f, b0 = 0.f, b1 = 0.f;
#pragma unroll
    for (int jj = 0; jj < 8; jj++) {
        float4 va = *(const float4*)(srcA + co[jj]);
        float4 vb = *(const float4*)(srcB + co[jj]);
        a0 = fmaf(Wa[4 * jj + 0], va.x, a0);
        a1 = fmaf(Wa[4 * jj + 1], va.y, a1);
        a0 = fmaf(Wa[4 * jj + 2], va.z, a0);
        a1 = fmaf(Wa[4 * jj + 3], va.w, a1);
        b0 = fmaf(Wb[4 * jj + 0], vb.x, b0);
        b1 = fmaf(Wb[4 * jj + 1], vb.y, b1);
        b0 = fmaf(Wb[4 * jj + 2], vb.z, b0);
        b1 = fmaf(Wb[4 * jj + 3], vb.w, b1);
    }
    oa = quad_red(a0 + a1);
    ob = quad_red(b0 + b1);
}

// four weights, one shared source
__device__ __forceinline__ void mv32_quad1(const float* __restrict__ Wa,
                                           const float* __restrict__ Wb,
                                           const float* __restrict__ Wc,
                                           const float* __restrict__ Wd,
                                           const float* __restrict__ src,
                                           const int co[8],
                                           float& oa, float& ob, float& oc, float& od)
{
    float a0 = 0.f, a1 = 0.f, b0 = 0.f, b1 = 0.f;
    float c0a = 0.f, c1 = 0.f, d0 = 0.f, d1 = 0.f;
#pragma unroll
    for (int jj = 0; jj < 8; jj++) {
        float4 v = *(const float4*)(src + co[jj]);
        a0 = fmaf(Wa[4 * jj + 0], v.x, a0);
        a1 = fmaf(Wa[4 * jj + 1], v.y, a1);
        a0 = fmaf(Wa[4 * jj + 2], v.z, a0);
        a1 = fmaf(Wa[4 * jj + 3], v.w, a1);
        b0 = fmaf(Wb[4 * jj + 0], v.x, b0);
        b1 = fmaf(Wb[4 * jj + 1], v.y, b1);
        b0 = fmaf(Wb[4 * jj + 2], v.z, b0);
        b1 = fmaf(Wb[4 * jj + 3], v.w, b1);
        c0a = fmaf(Wc[4 * jj + 0], v.x, c0a);
        c1 = fmaf(Wc[4 * jj + 1], v.y, c1);
        c0a = fmaf(Wc[4 * jj + 2], v.z, c0a);
        c1 = fmaf(Wc[4 * jj + 3], v.w, c1);
        d0 = fmaf(Wd[4 * jj + 0], v.x, d0);
        d1 = fmaf(Wd[4 * jj + 1], v.y, d1);
        d0 = fmaf(Wd[4 * jj + 2], v.z, d0);
        d1 = fmaf(Wd[4 * jj + 3], v.w, d1);
    }
    oa = quad_red(a0 + a1);
    ob = quad_red(b0 + b1);
    oc = quad_red(c0a + c1);
    od = quad_red(d0 + d1);
}

// ---------------------------------------------------------------------------
// Main recurrence: 1 WG / batch element, 512 threads, 9 serial stages / step.
//   f(h) = W2 tanh(W1 h + b1) + b2;  z_{i+1} = z1 + a (W12 u_i + W1b2)
//   h' = h + dts/6 * W2 S + dts b2, S = u1+2u2+2u3+u4
//   z1' = z1 + dts/6 * W12 S + dts W1b2   (shared stage with h')
//   gh  = Whh hA + dts/6 * Whh2 S' + dts Whhb2
// ---------------------------------------------------------------------------
__global__ __launch_bounds__(512, 1)
void rnn_kernel(const float* __restrict__ times,
                const float* __restrict__ W_hh, const float* __restrict__ b_hh,
                const float* __restrict__ W1, const float* __restrict__ b1,
                const float* __restrict__ W2, const float* __restrict__ b2,
                const float* __restrict__ W_mean, const float* __restrict__ b_mean,
                const float* __restrict__ W_logvar, const float* __restrict__ b_logvar,
                const float* __restrict__ W12, const float* __restrict__ Whh2,
                const float* __restrict__ w1b2v, const float* __restrict__ whhb2v,
                const float* __restrict__ gx,
                const float* __restrict__ x, const float* __restrict__ W_ih,
                const float* __restrict__ b_ih,
                const int use_gx,
                float* __restrict__ out)
{
    const int b = blockIdx.x;
    const int t = threadIdx.x;
    const int r = t >> 2;
    const int p = t & 3;
    const int c0 = 32 * p;

    __shared__ __align__(16) float shH[NH], shHA[NH], shU[NH], shS[NH];
    __shared__ float shT[NS];
    __shared__ __align__(16) float shGX[NG], shX[NI];

    // rotated column offsets: quad p starts at 16B-group (2p), disjoint banks
    int co[8];
#pragma unroll
    for (int jj = 0; jj < 8; jj++) co[jj] = c0 + 4 * ((jj + 2 * p) & 7);

    // ---- register-resident weights, pre-rotated to match co[] ----
    float w1r[32], w2r[32], w12r[32], wh0[32], wh1[32], wh2[32];
    float ws0[32], ws1[32], ws2[32];
#pragma unroll
    for (int jj = 0; jj < 8; jj++) {
        const int c = co[jj];
        *(float4*)&w1r[4 * jj]  = *(const float4*)&W1[r * NH + c];
        *(float4*)&w2r[4 * jj]  = *(const float4*)&W2[r * NH + c];
        *(float4*)&w12r[4 * jj] = *(const float4*)&W12[r * NH + c];
        *(float4*)&wh0[4 * jj]  = *(const float4*)&W_hh[(0 * NH + r) * NH + c];
        *(float4*)&wh1[4 * jj]  = *(const float4*)&W_hh[(1 * NH + r) * NH + c];
        *(float4*)&wh2[4 * jj]  = *(const float4*)&W_hh[(2 * NH + r) * NH + c];
        *(float4*)&ws0[4 * jj]  = *(const float4*)&Whh2[(size_t)(0 * NH + r) * NH + c];
        *(float4*)&ws1[4 * jj]  = *(const float4*)&Whh2[(size_t)(1 * NH + r) * NH + c];
        *(float4*)&ws2[4 * jj]  = *(const float4*)&Whh2[(size_t)(2 * NH + r) * NH + c];
    }
    const float b1r = b1[r], b2r = b2[r];
    const float bh0 = b_hh[r], bh1 = b_hh[NH + r], bh2 = b_hh[2 * NH + r];
    const float w1b2r = w1b2v[r];
    const float wb0 = whhb2v[r], wb1 = whhb2v[NH + r], wb2 = whhb2v[2 * NH + r];

    if (t < NS) shT[t] = times[t];
    if (t < NH) shH[t] = 0.f;
    __syncthreads();

    for (int si = 0; si < NS; ++si) {
        const int seq = NS - 1 - si;
        const float dt = (si == 0) ? 0.f : (shT[seq] - shT[seq + 1]);
        const float dts = 0.5f * dt;             // substep dt (N_SUB=2)
        const float a2 = 0.5f * dts;
        const float a6 = dts * (1.f / 6.f);

        // gx prefetch (consumed at stage 9)
        float gxr = 0.f, gxz = 0.f, gxn = 0.f;
        if (use_gx) {
            if (p == 0) {
                const float* g = gx + ((size_t)seq * NB + b) * NG;
                gxr = g[r]; gxz = g[NH + r]; gxn = g[2 * NH + r];
            }
        } else {
            if (t < NI) shX[t] = x[(b * NS + seq) * NI + t];
            __syncthreads();
            if (t < NG) {
                const float* wr = W_ih + t * NI;
                float a = 0.f;
#pragma unroll
                for (int cc = 0; cc < NI; cc += 4) {
                    float4 w4 = *(const float4*)(wr + cc);
                    a = fmaf(w4.x, shX[cc + 0], a);
                    a = fmaf(w4.y, shX[cc + 1], a);
                    a = fmaf(w4.z, shX[cc + 2], a);
                    a = fmaf(w4.w, shX[cc + 3], a);
                }
                shGX[t] = a + b_ih[t];
            }
            __syncthreads();
        }

        // ======== substep A ========
        // stage 1: z1 = W1 h + b1
        const float z1a = mv32(w1r, shH, co) + b1r;
        float u = fast_tanh(z1a);
        float S = u;
        if (p == 0) shU[r] = u;
        __syncthreads();
        // stage 2
        float m = mv32(w12r, shU, co);
        u = fast_tanh(z1a + a2 * (m + w1b2r));
        S += 2.f * u;
        if (p == 0) shU[r] = u;
        __syncthreads();
        // stage 3
        m = mv32(w12r, shU, co);
        u = fast_tanh(z1a + a2 * (m + w1b2r));
        S += 2.f * u;
        if (p == 0) shU[r] = u;
        __syncthreads();
        // stage 4 (a4 = dts)
        m = mv32(w12r, shU, co);
        u = fast_tanh(z1a + dts * (m + w1b2r));
        S += u;
        if (p == 0) shS[r] = S;
        __syncthreads();
        // stage 5: hA = h + a6 W2 S + dts b2 ; z1B = z1 + a6 W12 S + dts W1b2
        float mA, mB;
        mv32_pair1(w2r, w12r, shS, co, mA, mB);
        const float hA = shH[r] + a6 * mA + dts * b2r;
        const float z1b = z1a + a6 * mB + dts * w1b2r;
        u = fast_tanh(z1b);
        float S2 = u;
        if (p == 0) { shHA[r] = hA; shU[r] = u; }
        __syncthreads();

        // ======== substep B (+ Whh·hA folded in) ========
        float g0, g1, g2;
        // stage 6
        mv32_pair2(w12r, shU, wh0, shHA, co, m, g0);
        u = fast_tanh(z1b + a2 * (m + w1b2r));
        S2 += 2.f * u;
        if (p == 0) shU[r] = u;
        __syncthreads();
        // stage 7
        mv32_pair2(w12r, shU, wh1, shHA, co, m, g1);
        u = fast_tanh(z1b + a2 * (m + w1b2r));
        S2 += 2.f * u;
        if (p == 0) shU[r] = u;
        __syncthreads();
        // stage 8
        mv32_pair2(w12r, shU, wh2, shHA, co, m, g2);
        u = fast_tanh(z1b + dts * (m + w1b2r));
        S2 += u;
        if (p == 0) shS[r] = S2;
        __syncthreads();
        // stage 9: quad matvec over S2; GRU
        float n0, n1, n2, n3;
        mv32_quad1(w2r, ws0, ws1, ws2, shS, co, n0, n1, n2, n3);
        const float hB = hA + a6 * n0 + dts * b2r;
        const float rh = g0 + a6 * n1 + dts * wb0 + bh0;
        const float zh = g1 + a6 * n2 + dts * wb1 + bh1;
        const float nh = g2 + a6 * n3 + dts * wb2 + bh2;
        if (p == 0) {
            float rx, zx, nx;
            if (use_gx) { rx = gxr; zx = gxz; nx = gxn; }
            else        { rx = shGX[r]; zx = shGX[NH + r]; nx = shGX[2 * NH + r]; }
            const float rr = fast_sig(rx + rh);
            const float zz = fast_sig(zx + zh);
            const float nn = fast_tanh(nx + rr * nh);
            shH[r] = (1.f - zz) * nn + zz * hB;
        }
        __syncthreads();
    }

    // ---- epilogue: mean / logvar heads ----
    const int sel = r >> 6;
    const int l = r & 63;
    const float* Wf = sel ? W_logvar : W_mean;
    float a0 = 0.f, a1 = 0.f;
#pragma unroll
    for (int jj = 0; jj < 8; jj++) {
        const int c = co[jj];
        float4 w4 = *(const float4*)&Wf[l * NH + c];
        float4 h4 = *(const float4*)(shH + c);
        a0 = fmaf(w4.x, h4.x, a0);
        a1 = fmaf(w4.y, h4.y, a1);
        a0 = fmaf(w4.z, h4.z, a0);
        a1 = fmaf(w4.w, h4.w, a1);
    }
    float acc = quad_red(a0 + a1);
    if (p == 0) {
        const float bias = sel ? b_logvar[l] : b_mean[l];
        out[sel * (NB * NL) + b * NL + l] = acc + bias;
    }
}

extern "C" void kernel_launch(void* const* d_in, const int* in_sizes, int n_in,
                              void* d_out, int out_size, void* d_ws, size_t ws_size,
                              hipStream_t stream)
{
    const float* x        = (const float*)d_in[0];
    const float* times    = (const float*)d_in[1];
    const float* W_ih     = (const float*)d_in[2];
    const float* W_hh     = (const float*)d_in[3];
    const float* b_ih     = (const float*)d_in[4];
    const float* b_hh     = (const float*)d_in[5];
    const float* W1       = (const float*)d_in[6];
    const float* b1       = (const float*)d_in[7];
    const float* W2       = (const float*)d_in[8];
    const float* b2       = (const float*)d_in[9];
    const float* W_mean   = (const float*)d_in[10];
    const float* b_mean   = (const float*)d_in[11];
    const float* W_logvar = (const float*)d_in[12];
    const float* b_logvar = (const float*)d_in[13];
    float* out = (float*)d_out;

    // ws layout (floats): W12[16384] | Whh2[49152] | w1b2[128] | whhb2[384] | gx[...]
    float* wsf   = (float*)d_ws;
    float* W12   = wsf;
    float* Whh2  = wsf + 16384;
    float* w1b2  = wsf + 16384 + 49152;
    float* whhb2 = wsf + 16384 + 49152 + 128;
    float* gxbuf = wsf + 66048;
    const size_t need_full = (66048 + (size_t)NS * NB * NG) * sizeof(float);
    const int use_gx = (d_ws != nullptr && ws_size >= need_full) ? 1 : 0;

    if (use_gx) {
        gx_kernel<<<NS, 384, 0, stream>>>(x, W_ih, b_ih, gxbuf);
    }
    prep_kernel<<<512, 128, 0, stream>>>(W1, W_hh, W2, b2, W12, Whh2, w1b2, whhb2);
    rnn_kernel<<<NB, 512, 0, stream>>>(times, W_hh, b_hh, W1, b1, W2, b2,
                                       W_mean, b_mean, W_logvar, b_logvar,
                                       W12, Whh2, w1b2, whhb2,
                                       gxbuf, x, W_ih, b_ih, use_gx, out);
}

// Round 3
// 967.369 us; speedup vs baseline: 4.0619x; 4.0619x over previous
//
#include <hip/hip_runtime.h>

#define NB 128
#define NS 256
#define NI 64
#define NH 128
#define NL 64
#define NG 384  // 3*NH

typedef _Float16 f16;
typedef __attribute__((ext_vector_type(2))) _Float16 f16x2;

__device__ __forceinline__ float fast_tanh(float x) {
    float e = __expf(2.0f * x);
    return 1.0f - 2.0f / (e + 1.0f);
}
__device__ __forceinline__ float fast_sig(float x) {
    return 1.0f / (1.0f + __expf(-x));
}
__device__ __forceinline__ float quad_red(float a) {
    a += __shfl_xor(a, 1);
    a += __shfl_xor(a, 2);
    return a;
}
__device__ __forceinline__ float fdot2(f16x2 a, f16x2 b, float c) {
#if __has_builtin(__builtin_amdgcn_fdot2)
    return __builtin_amdgcn_fdot2(a, b, c, false);
#else
    return c + (float)a.x * (float)b.x + (float)a.y * (float)b.y;
#endif
}
__device__ __forceinline__ f16x2 bc16(unsigned int u) {
    return __builtin_bit_cast(f16x2, u);
}

// ---- f16 weight tables (pre-rounded once by prep_kernel) ----
__device__ __align__(16) f16 g_W1h[NH * NH];
__device__ __align__(16) f16 g_W2h[NH * NH];
__device__ __align__(16) f16 g_W12h[NH * NH];
__device__ __align__(16) f16 g_Whhh[3 * NH * NH];
__device__ __align__(16) f16 g_Whh2h[3 * NH * NH];
__device__ float g_w1b2[NH];
__device__ float g_whhb2[3 * NH];

// ---------------------------------------------------------------------------
// GX precompute: gx[s][b][j] = b_ih[j] + sum_c x[b][s][c] * W_ih[j][c]
// ---------------------------------------------------------------------------
__global__ __launch_bounds__(384)
void gx_kernel(const float* __restrict__ x, const float* __restrict__ W_ih,
               const float* __restrict__ b_ih, float* __restrict__ gx)
{
    const int s = blockIdx.x;
    const int j = threadIdx.x;
    __shared__ __align__(16) float xs[NB * NI];
    for (int idx = j; idx < NB * NI; idx += 384) {
        int bb = idx >> 6, cc = idx & 63;
        xs[idx] = x[(bb * NS + s) * NI + cc];
    }
    float w[64];
#pragma unroll
    for (int c = 0; c < 64; c += 4)
        *(float4*)&w[c] = *(const float4*)&W_ih[j * NI + c];
    const float bj = b_ih[j];
    __syncthreads();
    for (int bb = 0; bb < NB; bb++) {
        const float* xr = xs + bb * NI;
        float a0 = 0.f, a1 = 0.f, a2 = 0.f, a3 = 0.f;
#pragma unroll
        for (int c = 0; c < 64; c += 4) {
            a0 = fmaf(w[c + 0], xr[c + 0], a0);
            a1 = fmaf(w[c + 1], xr[c + 1], a1);
            a2 = fmaf(w[c + 2], xr[c + 2], a2);
            a3 = fmaf(w[c + 3], xr[c + 3], a3);
        }
        gx[((size_t)s * NB + bb) * NG + j] = ((a0 + a1) + (a2 + a3)) + bj;
    }
}

// ---------------------------------------------------------------------------
// Setup (fp32 math, then round to f16): W12=W1@W2, Whh2=Whh@W2, W1b2, Whhb2,
// plus f16 copies of W1, W2, Whh.
// ---------------------------------------------------------------------------
__global__ __launch_bounds__(128)
void prep_kernel(const float* __restrict__ W1, const float* __restrict__ Whh,
                 const float* __restrict__ W2, const float* __restrict__ b2)
{
    const int i = blockIdx.x;   // 0..511
    const int j = threadIdx.x;  // 0..127
    __shared__ float rowA[NH];
    __shared__ float red[NH];
    const float* src = (i < NH) ? (W1 + i * NH) : (Whh + (size_t)(i - NH) * NH);
    rowA[j] = src[j];
    __syncthreads();
    float acc = 0.f;
    for (int k = 0; k < NH; k++) acc = fmaf(rowA[k], W2[k * NH + j], acc);
    if (i < NH) {
        g_W12h[i * NH + j] = (f16)acc;
        g_W1h[i * NH + j]  = (f16)rowA[j];
        g_W2h[i * NH + j]  = (f16)W2[i * NH + j];
    } else {
        g_Whh2h[(size_t)(i - NH) * NH + j] = (f16)acc;
        g_Whhh[(size_t)(i - NH) * NH + j]  = (f16)rowA[j];
    }
    red[j] = rowA[j] * b2[j];
    __syncthreads();
    for (int off = 64; off > 0; off >>= 1) {
        if (j < off) red[j] += red[j + off];
        __syncthreads();
    }
    if (j == 0) {
        if (i < NH) g_w1b2[i] = red[0];
        else        g_whhb2[i - NH] = red[0];
    }
}

// ---------------------------------------------------------------------------
// dot2 helpers: thread owns 32 cols (c0..c0+31) as 4 rotated 16B chunks.
// All weight arrays are register f16x2[16] with literal indices (no scratch).
// ---------------------------------------------------------------------------
#define CH(SRC, OBX) (*(const uint4*)((const unsigned char*)(SRC) + (OBX)))

#define DSTEP1(W, K, V, A0, A1)                                                \
    A0 = fdot2(W[K + 0], bc16((V).x), A0);                                     \
    A1 = fdot2(W[K + 1], bc16((V).y), A1);                                     \
    A0 = fdot2(W[K + 2], bc16((V).z), A0);                                     \
    A1 = fdot2(W[K + 3], bc16((V).w), A1);

#define DOT1(W, SRC, OUT)                                                      \
    {                                                                          \
        float a0_ = 0.f, a1_ = 0.f;                                            \
        { uint4 v_ = CH(SRC, ob0); DSTEP1(W, 0,  v_, a0_, a1_) }               \
        { uint4 v_ = CH(SRC, ob1); DSTEP1(W, 4,  v_, a0_, a1_) }               \
        { uint4 v_ = CH(SRC, ob2); DSTEP1(W, 8,  v_, a0_, a1_) }               \
        { uint4 v_ = CH(SRC, ob3); DSTEP1(W, 12, v_, a0_, a1_) }               \
        OUT = quad_red(a0_ + a1_);                                             \
    }

// two weights, one shared source
#define DOT2S(WA, WB, SRC, OA, OB)                                             \
    {                                                                          \
        float a0_ = 0.f, a1_ = 0.f, b0_ = 0.f, b1_ = 0.f;                      \
        { uint4 v_ = CH(SRC, ob0); DSTEP1(WA, 0,  v_, a0_, a1_) DSTEP1(WB, 0,  v_, b0_, b1_) } \
        { uint4 v_ = CH(SRC, ob1); DSTEP1(WA, 4,  v_, a0_, a1_) DSTEP1(WB, 4,  v_, b0_, b1_) } \
        { uint4 v_ = CH(SRC, ob2); DSTEP1(WA, 8,  v_, a0_, a1_) DSTEP1(WB, 8,  v_, b0_, b1_) } \
        { uint4 v_ = CH(SRC, ob3); DSTEP1(WA, 12, v_, a0_, a1_) DSTEP1(WB, 12, v_, b0_, b1_) } \
        OA = quad_red(a0_ + a1_);                                              \
        OB = quad_red(b0_ + b1_);                                              \
    }

// two weights, two sources
#define DOT2D(WA, SA, WB, SB, OA, OB)                                          \
    {                                                                          \
        float a0_ = 0.f, a1_ = 0.f, b0_ = 0.f, b1_ = 0.f;                      \
        { uint4 v_ = CH(SA, ob0); uint4 u_ = CH(SB, ob0); DSTEP1(WA, 0,  v_, a0_, a1_) DSTEP1(WB, 0,  u_, b0_, b1_) } \
        { uint4 v_ = CH(SA, ob1); uint4 u_ = CH(SB, ob1); DSTEP1(WA, 4,  v_, a0_, a1_) DSTEP1(WB, 4,  u_, b0_, b1_) } \
        { uint4 v_ = CH(SA, ob2); uint4 u_ = CH(SB, ob2); DSTEP1(WA, 8,  v_, a0_, a1_) DSTEP1(WB, 8,  u_, b0_, b1_) } \
        { uint4 v_ = CH(SA, ob3); uint4 u_ = CH(SB, ob3); DSTEP1(WA, 12, v_, a0_, a1_) DSTEP1(WB, 12, u_, b0_, b1_) } \
        OA = quad_red(a0_ + a1_);                                              \
        OB = quad_red(b0_ + b1_);                                              \
    }

// four weights, one shared source
#define DOT4S(WA, WB, WC, WD, SRC, OA, OB, OC, OD)                             \
    {                                                                          \
        float a0_ = 0.f, a1_ = 0.f, b0_ = 0.f, b1_ = 0.f;                      \
        float c0_ = 0.f, c1_ = 0.f, d0_ = 0.f, d1_ = 0.f;                      \
        { uint4 v_ = CH(SRC, ob0); DSTEP1(WA, 0,  v_, a0_, a1_) DSTEP1(WB, 0,  v_, b0_, b1_) DSTEP1(WC, 0,  v_, c0_, c1_) DSTEP1(WD, 0,  v_, d0_, d1_) } \
        { uint4 v_ = CH(SRC, ob1); DSTEP1(WA, 4,  v_, a0_, a1_) DSTEP1(WB, 4,  v_, b0_, b1_) DSTEP1(WC, 4,  v_, c0_, c1_) DSTEP1(WD, 4,  v_, d0_, d1_) } \
        { uint4 v_ = CH(SRC, ob2); DSTEP1(WA, 8,  v_, a0_, a1_) DSTEP1(WB, 8,  v_, b0_, b1_) DSTEP1(WC, 8,  v_, c0_, c1_) DSTEP1(WD, 8,  v_, d0_, d1_) } \
        { uint4 v_ = CH(SRC, ob3); DSTEP1(WA, 12, v_, a0_, a1_) DSTEP1(WB, 12, v_, b0_, b1_) DSTEP1(WC, 12, v_, c0_, c1_) DSTEP1(WD, 12, v_, d0_, d1_) } \
        OA = quad_red(a0_ + a1_);                                              \
        OB = quad_red(b0_ + b1_);                                              \
        OC = quad_red(c0_ + c1_);                                              \
        OD = quad_red(d0_ + d1_);                                              \
    }

#define LOADW(DST, BASE)                                                       \
    {                                                                          \
        uint4 v0_ = *(const uint4*)((BASE) + cb0);                             \
        DST[0] = bc16(v0_.x); DST[1] = bc16(v0_.y); DST[2] = bc16(v0_.z); DST[3] = bc16(v0_.w); \
        uint4 v1_ = *(const uint4*)((BASE) + cb1);                             \
        DST[4] = bc16(v1_.x); DST[5] = bc16(v1_.y); DST[6] = bc16(v1_.z); DST[7] = bc16(v1_.w); \
        uint4 v2_ = *(const uint4*)((BASE) + cb2);                             \
        DST[8] = bc16(v2_.x); DST[9] = bc16(v2_.y); DST[10] = bc16(v2_.z); DST[11] = bc16(v2_.w); \
        uint4 v3_ = *(const uint4*)((BASE) + cb3);                             \
        DST[12] = bc16(v3_.x); DST[13] = bc16(v3_.y); DST[14] = bc16(v3_.z); DST[15] = bc16(v3_.w); \
    }

// ---------------------------------------------------------------------------
// Main recurrence: 1 WG / batch element, 512 threads (4 lanes per row),
// 9 serial stages / step, all weights register-resident as packed f16.
// ---------------------------------------------------------------------------
__global__ __launch_bounds__(512, 1)
void rnn_kernel(const float* __restrict__ times, const float* __restrict__ b_hh,
                const float* __restrict__ b1, const float* __restrict__ b2,
                const float* __restrict__ W_mean, const float* __restrict__ b_mean,
                const float* __restrict__ W_logvar, const float* __restrict__ b_logvar,
                const float* __restrict__ gx,
                const float* __restrict__ x, const float* __restrict__ W_ih,
                const float* __restrict__ b_ih,
                const int use_gx,
                float* __restrict__ out)
{
    const int b = blockIdx.x;
    const int t = threadIdx.x;
    const int r = t >> 2;
    const int p = t & 3;
    const int c0 = 32 * p;

    __shared__ __align__(16) f16 shHh[NH], shUh[NH], shAh[NH];
    __shared__ float shT[NS];
    __shared__ __align__(16) float shGX[NG], shX[NI], shHf[NH];

    // rotated chunk offsets (f16 units / bytes): quad p starts at chunk p
    const int cb0 = c0 + 8 * ((0 + p) & 3);
    const int cb1 = c0 + 8 * ((1 + p) & 3);
    const int cb2 = c0 + 8 * ((2 + p) & 3);
    const int cb3 = c0 + 8 * ((3 + p) & 3);
    const int ob0 = 2 * cb0, ob1 = 2 * cb1, ob2 = 2 * cb2, ob3 = 2 * cb3;

    // ---- register-resident packed-f16 weights (literal indices only) ----
    f16x2 w1p[16], w2p[16], w12p[16];
    f16x2 wh0p[16], wh1p[16], wh2p[16];
    f16x2 ws0p[16], ws1p[16], ws2p[16];
    LOADW(w1p,  g_W1h  + r * NH);
    LOADW(w2p,  g_W2h  + r * NH);
    LOADW(w12p, g_W12h + r * NH);
    LOADW(wh0p, g_Whhh + (0 * NH + r) * NH);
    LOADW(wh1p, g_Whhh + (1 * NH + r) * NH);
    LOADW(wh2p, g_Whhh + (2 * NH + r) * NH);
    LOADW(ws0p, g_Whh2h + (size_t)(0 * NH + r) * NH);
    LOADW(ws1p, g_Whh2h + (size_t)(1 * NH + r) * NH);
    LOADW(ws2p, g_Whh2h + (size_t)(2 * NH + r) * NH);

    const float b1r = b1[r], b2r = b2[r];
    const float bh0 = b_hh[r], bh1 = b_hh[NH + r], bh2 = b_hh[2 * NH + r];
    const float w1b2r = g_w1b2[r];
    const float wb0 = g_whhb2[r], wb1 = g_whhb2[NH + r], wb2 = g_whhb2[2 * NH + r];

    if (t < NS) shT[t] = times[t];
    if (t < NH) shHh[t] = (f16)0.f;
    float h = 0.f;  // fp32 h carried in registers (identical across the quad)
    __syncthreads();

    for (int si = 0; si < NS; ++si) {
        const int seq = NS - 1 - si;
        const float dt = (si == 0) ? 0.f : (shT[seq] - shT[seq + 1]);
        const float dts = 0.5f * dt;  // substep dt (N_SUB=2)
        const float a2 = 0.5f * dts;
        const float a6 = dts * (1.f / 6.f);

        // gx prefetch on ALL lanes (consumed at stage 9)
        float gxr = 0.f, gxz = 0.f, gxn = 0.f;
        if (use_gx) {
            const float* g = gx + ((size_t)seq * NB + b) * NG;
            gxr = g[r]; gxz = g[NH + r]; gxn = g[2 * NH + r];
        } else {
            if (t < NI) shX[t] = x[(b * NS + seq) * NI + t];
            __syncthreads();
            if (t < NG) {
                const float* wr = W_ih + t * NI;
                float a = 0.f;
#pragma unroll
                for (int cc = 0; cc < NI; cc += 4) {
                    float4 w4 = *(const float4*)(wr + cc);
                    a = fmaf(w4.x, shX[cc + 0], a);
                    a = fmaf(w4.y, shX[cc + 1], a);
                    a = fmaf(w4.z, shX[cc + 2], a);
                    a = fmaf(w4.w, shX[cc + 3], a);
                }
                shGX[t] = a + b_ih[t];
            }
            __syncthreads();
        }

        // ======== substep A ========
        float z1a, u, S, m;
        // stage 1: z1 = W1 h + b1
        DOT1(w1p, shHh, z1a);
        z1a += b1r;
        u = fast_tanh(z1a);
        S = u;
        if (p == 0) shUh[r] = (f16)u;
        __syncthreads();
        // stage 2
        DOT1(w12p, shUh, m);
        u = fast_tanh(z1a + a2 * (m + w1b2r));
        S += 2.f * u;
        if (p == 0) shUh[r] = (f16)u;
        __syncthreads();
        // stage 3
        DOT1(w12p, shUh, m);
        u = fast_tanh(z1a + a2 * (m + w1b2r));
        S += 2.f * u;
        if (p == 0) shUh[r] = (f16)u;
        __syncthreads();
        // stage 4 (k4 uses full dts)
        DOT1(w12p, shUh, m);
        u = fast_tanh(z1a + dts * (m + w1b2r));
        S += u;
        if (p == 0) shUh[r] = (f16)S;  // S becomes the stage-5 source
        __syncthreads();
        // stage 5: hA = h + a6 W2 S + dts b2 ; z1b = z1a + a6 W12 S + dts W1b2
        float mA, mB;
        DOT2S(w2p, w12p, shUh, mA, mB);
        const float hA = h + a6 * mA + dts * b2r;
        const float z1b = z1a + a6 * mB + dts * w1b2r;
        u = fast_tanh(z1b);
        float S2 = u;
        if (p == 0) { shAh[r] = (f16)hA; shUh[r] = (f16)u; }
        __syncthreads();

        // ======== substep B (+ Whh·hA folded in as pair-matvecs) ========
        float g0, g1, g2;
        // stage 6
        DOT2D(w12p, shUh, wh0p, shAh, m, g0);
        u = fast_tanh(z1b + a2 * (m + w1b2r));
        S2 += 2.f * u;
        if (p == 0) shUh[r] = (f16)u;
        __syncthreads();
        // stage 7
        DOT2D(w12p, shUh, wh1p, shAh, m, g1);
        u = fast_tanh(z1b + a2 * (m + w1b2r));
        S2 += 2.f * u;
        if (p == 0) shUh[r] = (f16)u;
        __syncthreads();
        // stage 8
        DOT2D(w12p, shUh, wh2p, shAh, m, g2);
        u = fast_tanh(z1b + dts * (m + w1b2r));
        S2 += u;
        if (p == 0) shUh[r] = (f16)S2;  // S2 becomes the stage-9 source
        __syncthreads();
        // stage 9: quad matvec over S2 ; GRU (computed on all lanes)
        float n0, n1, n2, n3;
        DOT4S(w2p, ws0p, ws1p, ws2p, shUh, n0, n1, n2, n3);
        const float hB = hA + a6 * n0 + dts * b2r;
        const float rh = g0 + a6 * n1 + dts * wb0 + bh0;
        const float zh = g1 + a6 * n2 + dts * wb1 + bh1;
        const float nh = g2 + a6 * n3 + dts * wb2 + bh2;
        float rx, zx, nx;
        if (use_gx) { rx = gxr; zx = gxz; nx = gxn; }
        else        { rx = shGX[r]; zx = shGX[NH + r]; nx = shGX[2 * NH + r]; }
        const float rr = fast_sig(rx + rh);
        const float zz = fast_sig(zx + zh);
        const float nn = fast_tanh(nx + rr * nh);
        h = (1.f - zz) * nn + zz * hB;
        if (p == 0) shHh[r] = (f16)h;
        __syncthreads();
    }

    // ---- epilogue: full-precision heads from fp32 h ----
    if (p == 0) shHf[r] = h;
    __syncthreads();
    const int sel = r >> 6;
    const int l = r & 63;
    const float* Wf = sel ? W_logvar : W_mean;
    float a0 = 0.f, a1 = 0.f;
#pragma unroll
    for (int jj = 0; jj < 8; jj++) {
        float4 w4 = *(const float4*)&Wf[l * NH + c0 + 4 * jj];
        float4 h4 = *(const float4*)(shHf + c0 + 4 * jj);
        a0 = fmaf(w4.x, h4.x, a0);
        a1 = fmaf(w4.y, h4.y, a1);
        a0 = fmaf(w4.z, h4.z, a0);
        a1 = fmaf(w4.w, h4.w, a1);
    }
    float acc = quad_red(a0 + a1);
    if (p == 0) {
        const float bias = sel ? b_logvar[l] : b_mean[l];
        out[sel * (NB * NL) + b * NL + l] = acc + bias;
    }
}

extern "C" void kernel_launch(void* const* d_in, const int* in_sizes, int n_in,
                              void* d_out, int out_size, void* d_ws, size_t ws_size,
                              hipStream_t stream)
{
    const float* x        = (const float*)d_in[0];
    const float* times    = (const float*)d_in[1];
    const float* W_ih     = (const float*)d_in[2];
    const float* W_hh     = (const float*)d_in[3];
    const float* b_ih     = (const float*)d_in[4];
    const float* b_hh     = (const float*)d_in[5];
    const float* W1       = (const float*)d_in[6];
    const float* b1       = (const float*)d_in[7];
    const float* W2       = (const float*)d_in[8];
    const float* b2       = (const float*)d_in[9];
    const float* W_mean   = (const float*)d_in[10];
    const float* b_mean   = (const float*)d_in[11];
    const float* W_logvar = (const float*)d_in[12];
    const float* b_logvar = (const float*)d_in[13];
    float* out = (float*)d_out;

    float* gxbuf = (float*)d_ws;
    const size_t need = (size_t)NS * NB * NG * sizeof(float);  // ~50.3 MB
    const int use_gx = (d_ws != nullptr && ws_size >= need) ? 1 : 0;

    if (use_gx) {
        gx_kernel<<<NS, 384, 0, stream>>>(x, W_ih, b_ih, gxbuf);
    }
    prep_kernel<<<512, 128, 0, stream>>>(W1, W_hh, W2, b2);
    rnn_kernel<<<NB, 512, 0, stream>>>(times, b_hh, b1, b2,
                                       W_mean, b_mean, W_logvar, b_logvar,
                                       gxbuf, x, W_ih, b_ih, use_gx, out);
}